// Round 9
// baseline (35.014 us; speedup 1.0000x reference)
//
#include <hip/hip_runtime.h>

#define NB 128
#define NQ 1000
#define NG 300
#define NK 4
#define THRESH 0.4f

#define GCHUNKS  12                // 300 = 12 x 25 GTs
#define GPERB    25                // GTs per block (fits one u32 bitmask)
#define NTHREADS 256
#define CAP      48                // per-GT candidate list capacity

// ---------------------------------------------------------------------------
// Single fused kernel, no workspace (d_ws re-poison costs ~39 us/replay).
//
// Round-8 post-mortem: (a) occupancy is the first-order lever (r5@32waves/CU
// = 28us beat r8@12waves/CU = 33us despite more LDS traffic); (b) the
// predicated LDS queue-push costs ~8-10 instr/test in exec-mask machinery.
// Round 9: branch-free hot loop -- the prefilter verdict is accumulated in a
// per-query-slot 32-bit mask, mask = (mask<<1)|pass (~2 instr), NO stores in
// the loop at all; drain walks the ~1.6 set bits/thread afterwards. LDS
// shrinks to ~3KB; grid (12,128)=1536 blocks = 6 blocks/CU = 24 waves/CU.
//
// Phase 1 exact conservative prefilter: iou>0.4 <=> 3.5*inter > pa+ta,
// tested as fma(inter,3.5,-0.999pa) >= 0.999ta (0.1% margin >> f32 rounding
// => no true positive dropped; rare false positives in iou~[0.3997,0.4]
// removed by phase 2's exact math).
// Phase 2 (4 lanes/GT): exact reference-identical math (full IEEE div, same
// epsilon/op order, sigmoid), top-4 via u64 keys (valbits<<32)|~q ==
// (value desc, index asc) = jax.lax.top_k order; bitonic merge masks 1,2
// (validated network); zero-filler indices = smallest unused q.
// Protocol validated absmax=0.0 in rounds 3-8.
// ---------------------------------------------------------------------------
__global__ __launch_bounds__(NTHREADS) void fused_matcher(
    const float* __restrict__ logits,      // [B,Q,1]
    const float* __restrict__ pboxes,      // [B,Q,4]
    const float* __restrict__ tboxes,      // [B,G,4]
    float* __restrict__ out_vals,          // [B,G,K]
    float* __restrict__ out_idx,           // [B,G,K] (as float)
    float* __restrict__ out_mask)          // [B,G,K] (0/1 float)
{
    __shared__ float4 stb[GPERB + 1];                 // GT boxes (+sentinel)
    __shared__ unsigned scnt[GPERB];                  // per-GT counts
    __shared__ unsigned short sslot[GPERB][CAP];      // per-GT candidate q's

    const int b   = blockIdx.y;
    const int gc  = blockIdx.x;
    const int tid = threadIdx.x;
    const int g0  = gc * GPERB;

    const float4* __restrict__ tb4 =
        reinterpret_cast<const float4*>(tboxes) + (size_t)b * NG + g0;
    const float4* __restrict__ pb4 =
        reinterpret_cast<const float4*>(pboxes) + (size_t)b * NQ;

    // ---- Stage: GT boxes to LDS; 4 query boxes to registers. ----
    if (tid < GPERB) {
        stb[tid]  = tb4[tid];
        scnt[tid] = 0u;
    }
    if (tid == GPERB) stb[GPERB] = make_float4(2e9f, 2e9f, 2e9f, 2e9f);

    const float4 dummy = make_float4(2e9f, 2e9f, 2e9f, 2e9f);
    float4 pA = pb4[tid];                                        // q = tid
    float4 pB = pb4[NTHREADS + tid];                             // q = 256+tid
    float4 pC = pb4[2 * NTHREADS + tid];                         // q = 512+tid
    float4 pD = (3 * NTHREADS + tid < NQ) ? pb4[3 * NTHREADS + tid] : dummy;
    const float aA = 0.999f * ((pA.z - pA.x) * (pA.w - pA.y));
    const float aB = 0.999f * ((pB.z - pB.x) * (pB.w - pB.y));
    const float aC = 0.999f * ((pC.z - pC.x) * (pC.w - pC.y));
    const float aD = 0.999f * ((pD.z - pD.x) * (pD.w - pD.y));   // 0 for dummy

    __syncthreads();

    // ---- Phase 1: 25 iterations, 4 branch-free register tests each.
    //      Verdicts go into per-slot bitmasks; NO memory ops except the
    //      1-ahead pipelined broadcast read of the next GT box. ----
    unsigned mA = 0u, mB = 0u, mC = 0u, mD = 0u;
    float4 tc = stb[0];
#define TEST(P, A, M)                                                       \
    {                                                                       \
        float ltx = fmaxf(P.x, tc.x);                                       \
        float lty = fmaxf(P.y, tc.y);                                       \
        float rbx = fminf(P.z, tc.z);                                       \
        float rby = fminf(P.w, tc.w);                                       \
        float w = fmaxf(rbx - ltx, 0.0f);                                   \
        float h = fmaxf(rby - lty, 0.0f);                                   \
        float inter = w * h;                                                \
        unsigned pass = (fmaf(inter, 3.5f, -(A)) >= ta999) ? 1u : 0u;       \
        M = (M << 1) | pass;                                                \
    }
#pragma unroll
    for (int gi = 0; gi < GPERB; ++gi) {
        float4 tn = stb[gi + 1];   // prefetch next GT box (broadcast read)
        const float ta999 = 0.999f * ((tc.z - tc.x) * (tc.w - tc.y));
        TEST(pA, aA, mA)
        TEST(pB, aB, mB)
        TEST(pC, aC, mC)
        TEST(pD, aD, mD)
        tc = tn;
    }
#undef TEST

    // ---- Drain bitmasks into per-GT lists (bit p <-> gi = GPERB-1-p). ----
#define DRAIN(M, SLOT)                                                      \
    while (M) {                                                             \
        int p  = __ffs(M) - 1;                                              \
        M &= M - 1u;                                                        \
        int gi = (GPERB - 1) - p;                                           \
        unsigned pos = atomicAdd(&scnt[gi], 1u);                            \
        if (pos < CAP)                                                      \
            sslot[gi][pos] = (unsigned short)((SLOT)*NTHREADS + tid);       \
    }
    DRAIN(mA, 0) DRAIN(mB, 1) DRAIN(mC, 2) DRAIN(mD, 3)
#undef DRAIN
    __syncthreads();

    // ---- Phase 2: exact select, 4 lanes per GT. ----
    const int grp = tid >> 2;    // GT within chunk
    const int l4  = tid & 3;
    if (grp < GPERB) {
        const float4 tb = stb[grp];
        const float tarea = (tb.z - tb.x) * (tb.w - tb.y);
        int n = (int)scnt[grp];
        if (n > CAP) n = CAP;
        const float* __restrict__ lg = logits + (size_t)b * NQ;

        unsigned long long k0 = 0ull, k1 = 0ull, k2 = 0ull, k3 = 0ull;
        for (int i = l4; i < n; i += 4) {
            const int q = sslot[grp][i];
            const float4 pp = pb4[q];
            float parea = (pp.z - pp.x) * (pp.w - pp.y);
            float ltx = fmaxf(pp.x, tb.x);
            float lty = fmaxf(pp.y, tb.y);
            float rbx = fminf(pp.z, tb.z);
            float rby = fminf(pp.w, tb.w);
            float w = fmaxf(rbx - ltx, 0.0f);
            float h = fmaxf(rby - lty, 0.0f);
            float inter = w * h;
            float uni   = parea + tarea - inter;
            float iou   = inter / (uni + 1e-7f);
            if (iou > THRESH) {
                float x   = lg[q];
                float sc  = 1.0f / (1.0f + expf(-x));
                float val = sc * iou;
                unsigned long long ck =
                    ((unsigned long long)__float_as_uint(val) << 32) |
                    (unsigned long long)(unsigned)(~(unsigned)q);
                if (ck > k3) {
                    if (ck > k0)      { k3 = k2; k2 = k1; k1 = k0; k0 = ck; }
                    else if (ck > k1) { k3 = k2; k2 = k1; k1 = ck; }
                    else if (ck > k2) { k3 = k2; k2 = ck; }
                    else              { k3 = ck; }
                }
            }
        }

        // Bitonic merge of sorted-4 lists across the 4-lane group.
#define MERGE_STEP(MASK)                                                    \
        {                                                                   \
            unsigned long long p0 = __shfl_xor(k0, MASK, 64);               \
            unsigned long long p1 = __shfl_xor(k1, MASK, 64);               \
            unsigned long long p2 = __shfl_xor(k2, MASK, 64);               \
            unsigned long long p3 = __shfl_xor(k3, MASK, 64);               \
            k0 = k0 > p3 ? k0 : p3;                                         \
            k1 = k1 > p2 ? k1 : p2;                                         \
            k2 = k2 > p1 ? k2 : p1;                                         \
            k3 = k3 > p0 ? k3 : p0;                                         \
            unsigned long long t;                                           \
            if (k0 < k2) { t = k0; k0 = k2; k2 = t; }                       \
            if (k1 < k3) { t = k1; k1 = k3; k3 = t; }                       \
            if (k0 < k1) { t = k0; k0 = k1; k1 = t; }                       \
            if (k2 < k3) { t = k2; k2 = k3; k3 = t; }                       \
        }
        MERGE_STEP(1)
        MERGE_STEP(2)
#undef MERGE_STEP

        if (l4 == 0) {
            const int iq0 = k0 ? (int)~(unsigned)k0 : -1;
            const int iq1 = k1 ? (int)~(unsigned)k1 : -1;
            const int iq2 = k2 ? (int)~(unsigned)k2 : -1;
            float4 vv, vi, vm;
            float* pv = &vv.x; float* pi_ = &vi.x; float* pm = &vm.x;
            int fill = 0;
#define EMIT(J, KJ)                                                         \
            {                                                               \
                if (KJ != 0ull) {                                           \
                    pv[J]  = __uint_as_float((unsigned)(KJ >> 32));         \
                    pi_[J] = (float)(int)~(unsigned)KJ;                     \
                    pm[J]  = 1.0f;                                          \
                } else {                                                    \
                    while (fill == iq0 || fill == iq1 || fill == iq2)       \
                        ++fill;                                             \
                    pv[J]  = 0.0f;                                          \
                    pi_[J] = (float)fill;                                   \
                    pm[J]  = 0.0f;                                          \
                    ++fill;                                                 \
                }                                                           \
            }
            EMIT(0, k0) EMIT(1, k1) EMIT(2, k2) EMIT(3, k3)
#undef EMIT
            const size_t o4 = (size_t)b * NG + g0 + grp;  // float4 index
            reinterpret_cast<float4*>(out_vals)[o4] = vv;
            reinterpret_cast<float4*>(out_idx)[o4]  = vi;
            reinterpret_cast<float4*>(out_mask)[o4] = vm;
        }
    }
}

extern "C" void kernel_launch(void* const* d_in, const int* in_sizes, int n_in,
                              void* d_out, int out_size, void* d_ws, size_t ws_size,
                              hipStream_t stream) {
    const float* logits = (const float*)d_in[0];  // [128,1000,1]
    const float* pboxes = (const float*)d_in[1];  // [128,1000,4]
    const float* tboxes = (const float*)d_in[2];  // [128,300,4]

    float* out = (float*)d_out;
    const size_t bgk = (size_t)NB * NG * NK;      // 153600
    float* out_vals = out;
    float* out_idx  = out + bgk;
    float* out_mask = out + 2 * bgk;

    dim3 grid(GCHUNKS, NB);                       // (12,128) = 1536 blocks
    fused_matcher<<<grid, NTHREADS, 0, stream>>>(logits, pboxes, tboxes,
                                                 out_vals, out_idx, out_mask);
}